// Round 4
// baseline (3689.655 us; speedup 1.0000x reference)
//
#include <hip/hip_runtime.h>
#include <math.h>

// Shapes: B=32, C=256, H=W=64 (HW=4096), ch=64, ac=384
// h buffer lives in d_out. ws: xt (8.39M f) + temp[5 ops] (41.9M f) + stats.

__device__ __forceinline__ float wave_sum(float v){
#pragma unroll
    for (int o = 32; o; o >>= 1) v += __shfl_down(v, o, 64);
    return v;
}
__device__ __forceinline__ float wave_max(float v){
#pragma unroll
    for (int o = 32; o; o >>= 1) v = fmaxf(v, __shfl_down(v, o, 64));
    return v;
}

// K1: per-(b,c) spatial mean & max of relu(src)
__global__ __launch_bounds__(256) void k_meanmax(const float* __restrict__ src,
                                                 float* __restrict__ meanb,
                                                 float* __restrict__ maxb){
    int bc = blockIdx.x, t = threadIdx.x;
    const float4* p = (const float4*)(src + ((size_t)bc << 12));
    float s = 0.f, m = 0.f;
    for (int i = t; i < 1024; i += 256){
        float4 v = p[i];
        float a = fmaxf(v.x, 0.f), b = fmaxf(v.y, 0.f), c = fmaxf(v.z, 0.f), d = fmaxf(v.w, 0.f);
        s += (a + b) + (c + d);
        m = fmaxf(m, fmaxf(fmaxf(a, b), fmaxf(c, d)));
    }
    s = wave_sum(s); m = wave_max(m);
    __shared__ float ss[4], sm_[4];
    int lane = t & 63, w = t >> 6;
    if (!lane){ ss[w] = s; sm_[w] = m; }
    __syncthreads();
    if (!t){
        meanb[bc] = (ss[0] + ss[1] + ss[2] + ss[3]) * (1.f / 4096.f);
        maxb[bc]  = fmaxf(fmaxf(sm_[0], sm_[1]), fmaxf(sm_[2], sm_[3]));
    }
}

// K2: nl = sigmoid(mlp(mean)+mlp(max)); w1:(128,256), w2:(256,128)
__global__ __launch_bounds__(256) void k_nl(const float* __restrict__ meanb, const float* __restrict__ maxb,
                                            const float* __restrict__ w1, const float* __restrict__ w2,
                                            float* __restrict__ nl){
    int b = blockIdx.x, t = threadIdx.x;
    __shared__ float sm[256], sx[256], hid[128];
    sm[t] = meanb[b * 256 + t]; sx[t] = maxb[b * 256 + t];
    __syncthreads();
    if (t < 128){
        float a = 0.f, c = 0.f;
        const float* wr = w1 + t * 256;
        for (int k = 0; k < 256; ++k){ float w = wr[k]; a = fmaf(w, sm[k], a); c = fmaf(w, sx[k], c); }
        hid[t] = fmaxf(a, 0.f) + fmaxf(c, 0.f);   // relu(h_mean)+relu(h_max), second matmul is linear
    }
    __syncthreads();
    float o = 0.f;
    const float* wr = w2 + t * 128;
    for (int j = 0; j < 128; ++j) o = fmaf(wr[j], hid[j], o);
    nl[b * 256 + t] = 1.f / (1.f + expf(-o));
}

// K2b: slist = nl.sum(0); stable top-64 (value desc, index asc) -> idx[64], selpos[256]
__global__ __launch_bounds__(256) void k_topk(const float* __restrict__ nl,
                                              int* __restrict__ idx, int* __restrict__ selpos){
    int t = threadIdx.x;
    __shared__ float sl[256];
    float s = 0.f;
    for (int b = 0; b < 32; ++b) s += nl[b * 256 + t];
    sl[t] = s; __syncthreads();
    float mys = sl[t];
    int rank = 0;
    for (int c = 0; c < 256; ++c){ float v = sl[c]; rank += (v > mys) || (v == mys && c < t); }
    selpos[t] = (rank < 64) ? rank : -1;
    if (rank < 64) idx[rank] = t;
}

// K3: dst = relu(src)*nl  (all 256 ch); also gather selected channels into xt
__global__ __launch_bounds__(256) void k_scale(const float* __restrict__ src, float* __restrict__ dst,
                                               float* __restrict__ xt, const float* __restrict__ nl,
                                               const int* __restrict__ selpos){
    int bc = blockIdx.x, t = threadIdx.x;
    int b = bc >> 8, c = bc & 255;
    float sc = nl[bc];
    int sp = selpos[c];
    const float4* s4 = (const float4*)(src + ((size_t)bc << 12));
    float4* d4 = (float4*)(dst + ((size_t)bc << 12));
    float4* x4 = (sp >= 0) ? (float4*)(xt + (((size_t)(b * 64 + sp)) << 12)) : (float4*)nullptr;
    for (int i = t; i < 1024; i += 256){
        float4 v = s4[i];
        v.x = fmaxf(v.x, 0.f) * sc; v.y = fmaxf(v.y, 0.f) * sc;
        v.z = fmaxf(v.z, 0.f) * sc; v.w = fmaxf(v.w, 0.f) * sc;
        d4[i] = v;
        if (sp >= 0) x4[i] = v;
    }
}

// K4: direct conv 1x1/3x3/5x5 on xt (64ch in, 64ch out).
// Thread owns a 1x8 strip (tile 32x64), OCB=4 oc per block -> per wave per ic:
// 15 ds_read_b128 vs 2240 FMA-issue cycles. Even at the measured ~29 cyc/read
// conflict cost, LDS/CU (~466K cyc) < FMA/SIMD (~573K cyc): FMA-issue-bound.
// Linear LDS layout stride 68 (round-3 plane-split swizzle ADDED conflicts on
// the staging writes; reverted). launch_bounds(256,3): cap 170 VGPR (natural
// live ~150: 96 acc + 12 window + 10 prefetch + 20 offsets), 3 blocks/CU.
// Ping-pong LDS + register prefetch: one barrier per ic.
#define OCB 4
__global__ __launch_bounds__(256, 3) void k_conv(const float* __restrict__ xt,
                                              const float* __restrict__ w1, const float* __restrict__ w3,
                                              const float* __restrict__ w5, float* __restrict__ temp){
    __shared__ __align__(16) float sm[2][2480];   // 36*68=2448 used + 32 pad
    int t = threadIdx.x;
    int k = t & 7;                // strip id: cols 8k..8k+7
    int ty = t >> 3;              // 0..31: row within tile
    int tile = blockIdx.x;        // 0..1
    int oc0 = blockIdx.y * OCB;   // 0..60
    int b = blockIdx.z;
    int ty0 = tile << 5;

    const float* base = xt + (((size_t)b * 64) << 12);

    // Staging offsets: 10 slots, halo element i = t + 256*s; halo (r,c) with
    // r in [0,36), c in [0,68); image (gy,gx) = (ty0-2+r, c-2). Linear LDS
    // word = i. Invalid lanes: load base[0], write distinct pad words.
    int goff[10], loff[10];
#pragma unroll
    for (int s = 0; s < 10; ++s){
        int i = t + 256 * s;
        int r = i / 68, c = i - r * 68;
        int gy = ty0 - 2 + r, gx = c - 2;
        bool ok = (i < 2448) && gy >= 0 && gy < 64 && gx >= 0 && gx < 64;
        goff[s] = ok ? ((gy << 6) + gx) : 0;
        loff[s] = ok ? i : (2448 + (t & 31));
    }

    // zero both buffers once (OOB halo slots never rewritten -> stay 0)
    for (int i = t; i < 2 * 2480; i += 256) ((float*)sm)[i] = 0.f;
    __syncthreads();
    // stage ic=0 into buf 0
#pragma unroll
    for (int s = 0; s < 10; ++s) sm[0][loff[s]] = base[goff[s]];
    __syncthreads();

    float a1[OCB][8], a3[OCB][8], a5[OCB][8];
#pragma unroll
    for (int o = 0; o < OCB; ++o)
#pragma unroll
        for (int px = 0; px < 8; ++px){ a1[o][px] = 0.f; a3[o][px] = 0.f; a5[o][px] = 0.f; }

    for (int ic = 0; ic < 64; ++ic){
        int cur = ic & 1, nxt = cur ^ 1;
        // prefetch next plane into registers (hidden under FMA block)
        float g[10];
        if (ic < 63){
            const float* src = base + ((size_t)(ic + 1) << 12);
#pragma unroll
            for (int s = 0; s < 10; ++s) g[s] = src[goff[s]];
        }

        const float* smc = sm[cur];
#pragma unroll
        for (int dy = 0; dy < 5; ++dy){
            const float* rowb = smc + (ty + dy) * 68 + (k << 3);
            float4 A = *(const float4*)(rowb);
            float4 Bv = *(const float4*)(rowb + 4);
            float4 Cv = *(const float4*)(rowb + 8);
            float v[12] = {A.x, A.y, A.z, A.w, Bv.x, Bv.y, Bv.z, Bv.w, Cv.x, Cv.y, Cv.z, Cv.w};

#pragma unroll
            for (int o = 0; o < OCB; ++o){
                const float* W5r = w5 + (size_t)((oc0 + o) * 64 + ic) * 25 + dy * 5;
                float w50 = W5r[0], w51 = W5r[1], w52 = W5r[2], w53 = W5r[3], w54 = W5r[4];
#pragma unroll
                for (int px = 0; px < 8; ++px){
                    float acc = a5[o][px];
                    acc = fmaf(v[px + 0], w50, acc);
                    acc = fmaf(v[px + 1], w51, acc);
                    acc = fmaf(v[px + 2], w52, acc);
                    acc = fmaf(v[px + 3], w53, acc);
                    acc = fmaf(v[px + 4], w54, acc);
                    a5[o][px] = acc;
                }
            }
            if (dy >= 1 && dy <= 3){
#pragma unroll
                for (int o = 0; o < OCB; ++o){
                    const float* W3r = w3 + (size_t)((oc0 + o) * 64 + ic) * 9 + (dy - 1) * 3;
                    float w30 = W3r[0], w31 = W3r[1], w32 = W3r[2];
#pragma unroll
                    for (int px = 0; px < 8; ++px){
                        float acc = a3[o][px];
                        acc = fmaf(v[px + 1], w30, acc);
                        acc = fmaf(v[px + 2], w31, acc);
                        acc = fmaf(v[px + 3], w32, acc);
                        a3[o][px] = acc;
                    }
                }
                if (dy == 2){
#pragma unroll
                    for (int o = 0; o < OCB; ++o){
                        float w10 = w1[(oc0 + o) * 64 + ic];
#pragma unroll
                        for (int px = 0; px < 8; ++px)
                            a1[o][px] = fmaf(v[px + 2], w10, a1[o][px]);
                    }
                }
            }
        }

        // commit prefetched plane to the other buffer; single barrier per ic
        if (ic < 63){
#pragma unroll
            for (int s = 0; s < 10; ++s) sm[nxt][loff[s]] = g[s];
        }
        __syncthreads();
    }

    // write out: 1x8 strip per thread -> 2 float4 per (conv, oc)
    int y = ty0 + ty;
    size_t pix = ((size_t)y << 6) + (k << 3);
    size_t bb = (size_t)b * 320;  // b*5*64
#pragma unroll
    for (int o = 0; o < OCB; ++o){
        int oc = oc0 + o;
        float* p1 = temp + (((bb + oc) << 12) + pix);
        float* p3 = temp + (((bb + 64 + oc) << 12) + pix);
        float* p5 = temp + (((bb + 128 + oc) << 12) + pix);
        *(float4*)(p1)     = make_float4(a1[o][0], a1[o][1], a1[o][2], a1[o][3]);
        *(float4*)(p1 + 4) = make_float4(a1[o][4], a1[o][5], a1[o][6], a1[o][7]);
        *(float4*)(p3)     = make_float4(a3[o][0], a3[o][1], a3[o][2], a3[o][3]);
        *(float4*)(p3 + 4) = make_float4(a3[o][4], a3[o][5], a3[o][6], a3[o][7]);
        *(float4*)(p5)     = make_float4(a5[o][0], a5[o][1], a5[o][2], a5[o][3]);
        *(float4*)(p5 + 4) = make_float4(a5[o][4], a5[o][5], a5[o][6], a5[o][7]);
    }
}

// K5: 3x3 avg (count-normalized) + max pool; xt >= 0 so zero OOB fill is valid for both
__global__ __launch_bounds__(256) void k_pool(const float* __restrict__ xt, float* __restrict__ temp){
    __shared__ float sm[18][18];
    int t = threadIdx.x;
    int tx = t & 15, ty = t >> 4;
    int tile = blockIdx.x, c = blockIdx.y, b = blockIdx.z;
    int ty0 = (tile >> 2) * 16, tx0 = (tile & 3) * 16;
    const float* src = xt + (((size_t)b * 64 + c) << 12);
    for (int i = t; i < 324; i += 256){
        int r = i / 18, cc = i - r * 18;
        int gy = ty0 - 1 + r, gx = tx0 - 1 + cc;
        sm[r][cc] = (gy >= 0 && gy < 64 && gx >= 0 && gx < 64) ? src[(gy << 6) + gx] : 0.f;
    }
    __syncthreads();
    float s = 0.f, m = 0.f;
#pragma unroll
    for (int ky = 0; ky < 3; ++ky)
#pragma unroll
        for (int kx = 0; kx < 3; ++kx){ float v = sm[ty + ky][tx + kx]; s += v; m = fmaxf(m, v); }
    int y = ty0 + ty, x = tx0 + tx;
    int cy = min(y + 1, 63) - max(y - 1, 0) + 1;
    int cx = min(x + 1, 63) - max(x - 1, 0) + 1;
    size_t pix = ((size_t)y << 6) + x;
    size_t bb = (size_t)b * 320;
    temp[((bb + 192 + c) << 12) + pix] = s / (float)(cy * cx);
    temp[((bb + 256 + c) << 12) + pix] = m;
}

// K6: spatial sums of all 384 concat channels (ops 3/4 raw pool sums; op5 from xt)
__global__ __launch_bounds__(256) void k_smean(const float* __restrict__ temp, const float* __restrict__ xt,
                                               float* __restrict__ tsum){
    int opc = blockIdx.x, b = blockIdx.y, t = threadIdx.x;
    const float* src;
    if (opc < 320){
        src = temp + (((size_t)b * 320 + opc) << 12);
    } else {
        src = xt + (((size_t)b * 64 + (opc - 320)) << 12);
    }
    const float4* p = (const float4*)src;
    float s = 0.f;
    for (int i = t; i < 1024; i += 256){ float4 v = p[i]; s += (v.x + v.y) + (v.z + v.w); }
    s = wave_sum(s);
    __shared__ float ss[4];
    int lane = t & 63, w = t >> 6;
    if (!lane) ss[w] = s;
    __syncthreads();
    if (!t) tsum[b * 384 + opc] = ss[0] + ss[1] + ss[2] + ss[3];
}

// K6b: BN stats (mean, rsqrt(var+eps)) over (B,H,W) for the 128 pool channels
__global__ __launch_bounds__(256) void k_bnstats(const float* __restrict__ temp,
                                                 float* __restrict__ bn_m, float* __restrict__ bn_r){
    int q = blockIdx.x, t = threadIdx.x;     // q: 0..127 -> op=3+q/64, c=q%64
    int opc = 192 + q;                        // channel offset within b*320 block
    float s = 0.f, s2 = 0.f;
    for (int b = 0; b < 32; ++b){
        const float4* p = (const float4*)(temp + (((size_t)b * 320 + opc) << 12));
        for (int i = t; i < 1024; i += 256){
            float4 v = p[i];
            s += (v.x + v.y) + (v.z + v.w);
            s2 = fmaf(v.x, v.x, s2); s2 = fmaf(v.y, v.y, s2);
            s2 = fmaf(v.z, v.z, s2); s2 = fmaf(v.w, v.w, s2);
        }
    }
    s = wave_sum(s); s2 = wave_sum(s2);
    __shared__ float ss[4], ss2[4];
    int lane = t & 63, w = t >> 6;
    if (!lane){ ss[w] = s; ss2[w] = s2; }
    __syncthreads();
    if (!t){
        float S = ss[0] + ss[1] + ss[2] + ss[3], S2 = ss2[0] + ss2[1] + ss2[2] + ss2[3];
        const float N = 131072.f;
        float m = S / N;
        float var = S2 / N - m * m;
        bn_m[q] = m;
        bn_r[q] = rsqrtf(var + 1e-5f);
    }
}

// K7: y = sigmoid(relu(tm @ w1.T) @ w2.T); tm adjusts ops3/4 by BN. w1:(48,384), w2:(384,48)
__global__ __launch_bounds__(384) void k_att(const float* __restrict__ tsum, const float* __restrict__ bn_m,
                                             const float* __restrict__ bn_r,
                                             const float* __restrict__ w1, const float* __restrict__ w2,
                                             float* __restrict__ yv){
    int b = blockIdx.x, t = threadIdx.x;
    __shared__ float tm[384], hid[48];
    float v = tsum[b * 384 + t] * (1.f / 4096.f);
    if (t >= 192 && t < 320){ int q = t - 192; v = (v - bn_m[q]) * bn_r[q]; }
    tm[t] = v; __syncthreads();
    if (t < 48){
        float a = 0.f; const float* wr = w1 + t * 384;
        for (int k = 0; k < 384; ++k) a = fmaf(wr[k], tm[k], a);
        hid[t] = fmaxf(a, 0.f);
    }
    __syncthreads();
    float o = 0.f; const float* wr = w2 + t * 48;
    for (int j = 0; j < 48; ++j) o = fmaf(wr[j], hid[j], o);
    yv[b * 384 + t] = 1.f / (1.f + expf(-o));
}

// K8: out = sum_op y_op * op_val (BN folded); scatter to h[:, idx[c]]
__global__ __launch_bounds__(256) void k_combine(const float* __restrict__ temp, const float* __restrict__ xt,
                                                 const float* __restrict__ yv, const float* __restrict__ bn_m,
                                                 const float* __restrict__ bn_r, const int* __restrict__ idxp,
                                                 float* __restrict__ h){
    int c = blockIdx.x, b = blockIdx.y, t = threadIdx.x;
    const float* yb = yv + b * 384;
    float y0 = yb[c], y1 = yb[64 + c], y2 = yb[128 + c];
    float y3 = yb[192 + c], y4 = yb[256 + c], y5 = yb[320 + c];
    float m3 = bn_m[c], r3 = bn_r[c], m4 = bn_m[64 + c], r4 = bn_r[64 + c];
    float a3 = y3 * r3, c3 = -y3 * r3 * m3, a4 = y4 * r4, c4 = -y4 * r4 * m4;
    float bias = c3 + c4;
    size_t base = (((size_t)b * 320 + c) << 12);
    const float4* t0 = (const float4*)(temp + base);
    const float4* t1 = (const float4*)(temp + base + (64ull << 12));
    const float4* t2 = (const float4*)(temp + base + (128ull << 12));
    const float4* t3 = (const float4*)(temp + base + (192ull << 12));
    const float4* t4 = (const float4*)(temp + base + (256ull << 12));
    const float4* t5 = (const float4*)(xt + (((size_t)b * 64 + c) << 12));
    float4* o4 = (float4*)(h + (((size_t)(b * 256 + idxp[c])) << 12));
    for (int i = t; i < 1024; i += 256){
        float4 v0 = t0[i], v1 = t1[i], v2 = t2[i], v3 = t3[i], v4 = t4[i], v5 = t5[i];
        float4 r;
        r.x = y0 * v0.x + y1 * v1.x + y2 * v2.x + a3 * v3.x + a4 * v4.x + y5 * v5.x + bias;
        r.y = y0 * v0.y + y1 * v1.y + y2 * v2.y + a3 * v3.y + a4 * v4.y + y5 * v5.y + bias;
        r.z = y0 * v0.z + y1 * v1.z + y2 * v2.z + a3 * v3.z + a4 * v4.z + y5 * v5.z + bias;
        r.w = y0 * v0.w + y1 * v1.w + y2 * v2.w + a3 * v3.w + a4 * v4.w + y5 * v5.w + bias;
        o4[i] = r;
    }
}

// K9: d_out += x
__global__ __launch_bounds__(256) void k_addx(const float* __restrict__ x, float* __restrict__ out){
    const float4* x4 = (const float4*)x;
    float4* o4 = (float4*)out;
    for (int i = blockIdx.x * 256 + threadIdx.x; i < 8388608; i += 8192 * 256){
        float4 a = x4[i], b = o4[i];
        b.x += a.x; b.y += a.y; b.z += a.z; b.w += a.w;
        o4[i] = b;
    }
}

extern "C" void kernel_launch(void* const* d_in, const int* in_sizes, int n_in,
                              void* d_out, int out_size, void* d_ws, size_t ws_size,
                              hipStream_t stream){
    const float* x = (const float*)d_in[0];
    float* h = (float*)d_out;                 // h buffer lives in d_out
    float* ws = (float*)d_ws;
    float* xt    = ws;                        // 8,388,608 floats
    float* temp  = ws + 8388608;              // 41,943,040 floats (5 ops)
    float* small = ws + 8388608 + 41943040;
    float* meanb = small;                     // 8192
    float* maxb  = small + 8192;              // 8192
    float* nl    = small + 16384;             // 8192
    float* tsum  = small + 24576;             // 12288
    float* bn_m  = small + 36864;             // 128
    float* bn_r  = small + 36992;             // 128
    float* yv    = small + 37120;             // 12288
    int*   idxp  = (int*)(small + 49408);     // 64
    int*   selp  = idxp + 64;                 // 256

    for (int r = 0; r < 2; ++r){
        const float* ca_w1 = (const float*)d_in[2 + r * 7];
        const float* ca_w2 = (const float*)d_in[3 + r * 7];
        const float* w1    = (const float*)d_in[4 + r * 7];
        const float* w3    = (const float*)d_in[5 + r * 7];
        const float* w5    = (const float*)d_in[6 + r * 7];
        const float* a_w1  = (const float*)d_in[7 + r * 7];
        const float* a_w2  = (const float*)d_in[8 + r * 7];
        const float* src = (r == 0) ? x : h;

        hipLaunchKernelGGL(k_meanmax, dim3(8192), dim3(256), 0, stream, src, meanb, maxb);
        hipLaunchKernelGGL(k_nl,      dim3(32),   dim3(256), 0, stream, meanb, maxb, ca_w1, ca_w2, nl);
        hipLaunchKernelGGL(k_topk,    dim3(1),    dim3(256), 0, stream, nl, idxp, selp);
        hipLaunchKernelGGL(k_scale,   dim3(8192), dim3(256), 0, stream, src, h, xt, nl, selp);
        hipLaunchKernelGGL(k_conv,    dim3(2, 16, 32),  dim3(256), 0, stream, xt, w1, w3, w5, temp);
        hipLaunchKernelGGL(k_pool,    dim3(16, 64, 32), dim3(256), 0, stream, xt, temp);
        hipLaunchKernelGGL(k_smean,   dim3(384, 32),    dim3(256), 0, stream, temp, xt, tsum);
        hipLaunchKernelGGL(k_bnstats, dim3(128),  dim3(256), 0, stream, temp, bn_m, bn_r);
        hipLaunchKernelGGL(k_att,     dim3(32),   dim3(384), 0, stream, tsum, bn_m, bn_r, a_w1, a_w2, yv);
        hipLaunchKernelGGL(k_combine, dim3(64, 32), dim3(256), 0, stream, temp, xt, yv, bn_m, bn_r, idxp, h);
    }
    hipLaunchKernelGGL(k_addx, dim3(8192), dim3(256), 0, stream, x, h);
}

// Round 5
// 1715.334 us; speedup vs baseline: 2.1510x; 2.1510x over previous
//
#include <hip/hip_runtime.h>
#include <math.h>

// Shapes: B=32, C=256, H=W=64 (HW=4096), ch=64, ac=384
// h buffer lives in d_out. ws: xt (8.39M f) + temp[5 ops] (41.9M f) + stats.

__device__ __forceinline__ float wave_sum(float v){
#pragma unroll
    for (int o = 32; o; o >>= 1) v += __shfl_down(v, o, 64);
    return v;
}
__device__ __forceinline__ float wave_max(float v){
#pragma unroll
    for (int o = 32; o; o >>= 1) v = fmaxf(v, __shfl_down(v, o, 64));
    return v;
}

// K1: per-(b,c) spatial mean & max of relu(src)
__global__ __launch_bounds__(256) void k_meanmax(const float* __restrict__ src,
                                                 float* __restrict__ meanb,
                                                 float* __restrict__ maxb){
    int bc = blockIdx.x, t = threadIdx.x;
    const float4* p = (const float4*)(src + ((size_t)bc << 12));
    float s = 0.f, m = 0.f;
    for (int i = t; i < 1024; i += 256){
        float4 v = p[i];
        float a = fmaxf(v.x, 0.f), b = fmaxf(v.y, 0.f), c = fmaxf(v.z, 0.f), d = fmaxf(v.w, 0.f);
        s += (a + b) + (c + d);
        m = fmaxf(m, fmaxf(fmaxf(a, b), fmaxf(c, d)));
    }
    s = wave_sum(s); m = wave_max(m);
    __shared__ float ss[4], sm_[4];
    int lane = t & 63, w = t >> 6;
    if (!lane){ ss[w] = s; sm_[w] = m; }
    __syncthreads();
    if (!t){
        meanb[bc] = (ss[0] + ss[1] + ss[2] + ss[3]) * (1.f / 4096.f);
        maxb[bc]  = fmaxf(fmaxf(sm_[0], sm_[1]), fmaxf(sm_[2], sm_[3]));
    }
}

// K2: nl = sigmoid(mlp(mean)+mlp(max)); w1:(128,256), w2:(256,128)
__global__ __launch_bounds__(256) void k_nl(const float* __restrict__ meanb, const float* __restrict__ maxb,
                                            const float* __restrict__ w1, const float* __restrict__ w2,
                                            float* __restrict__ nl){
    int b = blockIdx.x, t = threadIdx.x;
    __shared__ float sm[256], sx[256], hid[128];
    sm[t] = meanb[b * 256 + t]; sx[t] = maxb[b * 256 + t];
    __syncthreads();
    if (t < 128){
        float a = 0.f, c = 0.f;
        const float* wr = w1 + t * 256;
        for (int k = 0; k < 256; ++k){ float w = wr[k]; a = fmaf(w, sm[k], a); c = fmaf(w, sx[k], c); }
        hid[t] = fmaxf(a, 0.f) + fmaxf(c, 0.f);   // relu(h_mean)+relu(h_max), second matmul is linear
    }
    __syncthreads();
    float o = 0.f;
    const float* wr = w2 + t * 128;
    for (int j = 0; j < 128; ++j) o = fmaf(wr[j], hid[j], o);
    nl[b * 256 + t] = 1.f / (1.f + expf(-o));
}

// K2b: slist = nl.sum(0); stable top-64 (value desc, index asc) -> idx[64], selpos[256]
__global__ __launch_bounds__(256) void k_topk(const float* __restrict__ nl,
                                              int* __restrict__ idx, int* __restrict__ selpos){
    int t = threadIdx.x;
    __shared__ float sl[256];
    float s = 0.f;
    for (int b = 0; b < 32; ++b) s += nl[b * 256 + t];
    sl[t] = s; __syncthreads();
    float mys = sl[t];
    int rank = 0;
    for (int c = 0; c < 256; ++c){ float v = sl[c]; rank += (v > mys) || (v == mys && c < t); }
    selpos[t] = (rank < 64) ? rank : -1;
    if (rank < 64) idx[rank] = t;
}

// K3: dst = relu(src)*nl  (all 256 ch); also gather selected channels into xt
__global__ __launch_bounds__(256) void k_scale(const float* __restrict__ src, float* __restrict__ dst,
                                               float* __restrict__ xt, const float* __restrict__ nl,
                                               const int* __restrict__ selpos){
    int bc = blockIdx.x, t = threadIdx.x;
    int b = bc >> 8, c = bc & 255;
    float sc = nl[bc];
    int sp = selpos[c];
    const float4* s4 = (const float4*)(src + ((size_t)bc << 12));
    float4* d4 = (float4*)(dst + ((size_t)bc << 12));
    float4* x4 = (sp >= 0) ? (float4*)(xt + (((size_t)(b * 64 + sp)) << 12)) : (float4*)nullptr;
    for (int i = t; i < 1024; i += 256){
        float4 v = s4[i];
        v.x = fmaxf(v.x, 0.f) * sc; v.y = fmaxf(v.y, 0.f) * sc;
        v.z = fmaxf(v.z, 0.f) * sc; v.w = fmaxf(v.w, 0.f) * sc;
        d4[i] = v;
        if (sp >= 0) x4[i] = v;
    }
}

// K4: direct conv 1x1/3x3/5x5 on xt (64ch in, 64ch out).
// PX=4, OCB=4: thread owns a 1x4 strip, tile 16 rows x 64 cols, lane map
// k=t&15 (strip), ty=t>>4. A wave's b128 read is serviced in 16-lane phases;
// here each phase = one row's 16 CONSECUTIVE float4s (256B contiguous) =
// conflict-free minimum (rounds 2-4 layouts had same-bank/different-row
// pairs inside each phase -> ~34 extra cyc/read). Per (ic,dy): 2 b128 reads
// (8-float window); per wave per ic: 10 LDS instr vs 1120 FMA cyc (~10:1).
// Natural live ~82 (48 acc + 8 win + 6 prefetch + addr) -- under the ~90
// limit this allocator handles (r3: 88 ok; r4: 150 -> scratch spill 3.2GB).
// Ping-pong LDS + register prefetch, one barrier per ic.
#define OCB 4
__global__ __launch_bounds__(256, 3) void k_conv(const float* __restrict__ xt,
                                              const float* __restrict__ w1, const float* __restrict__ w3,
                                              const float* __restrict__ w5, float* __restrict__ temp){
    __shared__ __align__(16) float sm[2][1392];   // 20*68=1360 used + 32 pad
    int t = threadIdx.x;
    int k = t & 15;               // strip id: cols 4k..4k+3
    int ty = t >> 4;              // 0..15: row within tile
    int tile = blockIdx.x;        // 0..3
    int oc0 = blockIdx.y * OCB;   // 0..60
    int b = blockIdx.z;
    int ty0 = tile << 4;

    const float* base = xt + (((size_t)b * 64) << 12);

    // Staging offsets: 6 slots, halo element i = t + 256*s; halo (r,c) with
    // r in [0,20), c in [0,68); image (gy,gx) = (ty0-2+r, c-2). Linear LDS
    // word = i. Invalid lanes: load base[0], write pad words 1360+.
    int goff[6], loff[6];
#pragma unroll
    for (int s = 0; s < 6; ++s){
        int i = t + 256 * s;
        int r = i / 68, c = i - r * 68;
        int gy = ty0 - 2 + r, gx = c - 2;
        bool ok = (i < 1360) && gy >= 0 && gy < 64 && gx >= 0 && gx < 64;
        goff[s] = ok ? ((gy << 6) + gx) : 0;
        loff[s] = ok ? i : (1360 + (t & 31));
    }

    // zero both buffers once (OOB halo slots never rewritten -> stay 0)
    for (int i = t; i < 2 * 1392; i += 256) ((float*)sm)[i] = 0.f;
    __syncthreads();
    // stage ic=0 into buf 0
#pragma unroll
    for (int s = 0; s < 6; ++s) sm[0][loff[s]] = base[goff[s]];
    __syncthreads();

    float a1[OCB][4], a3[OCB][4], a5[OCB][4];
#pragma unroll
    for (int o = 0; o < OCB; ++o)
#pragma unroll
        for (int px = 0; px < 4; ++px){ a1[o][px] = 0.f; a3[o][px] = 0.f; a5[o][px] = 0.f; }

    for (int ic = 0; ic < 64; ++ic){
        int cur = ic & 1, nxt = cur ^ 1;
        // prefetch next plane into registers (hidden under FMA block)
        float g[6];
        if (ic < 63){
            const float* src = base + ((size_t)(ic + 1) << 12);
#pragma unroll
            for (int s = 0; s < 6; ++s) g[s] = src[goff[s]];
        }

        const float* smc = sm[cur];
#pragma unroll
        for (int dy = 0; dy < 5; ++dy){
            const float* rowb = smc + (ty + dy) * 68 + (k << 2);
            float4 A = *(const float4*)(rowb);
            float4 Bv = *(const float4*)(rowb + 4);
            float v[8] = {A.x, A.y, A.z, A.w, Bv.x, Bv.y, Bv.z, Bv.w};

#pragma unroll
            for (int o = 0; o < OCB; ++o){
                const float* W5r = w5 + (size_t)((oc0 + o) * 64 + ic) * 25 + dy * 5;
                float w50 = W5r[0], w51 = W5r[1], w52 = W5r[2], w53 = W5r[3], w54 = W5r[4];
#pragma unroll
                for (int px = 0; px < 4; ++px){
                    float acc = a5[o][px];
                    acc = fmaf(v[px + 0], w50, acc);
                    acc = fmaf(v[px + 1], w51, acc);
                    acc = fmaf(v[px + 2], w52, acc);
                    acc = fmaf(v[px + 3], w53, acc);
                    acc = fmaf(v[px + 4], w54, acc);
                    a5[o][px] = acc;
                }
            }
            if (dy >= 1 && dy <= 3){
#pragma unroll
                for (int o = 0; o < OCB; ++o){
                    const float* W3r = w3 + (size_t)((oc0 + o) * 64 + ic) * 9 + (dy - 1) * 3;
                    float w30 = W3r[0], w31 = W3r[1], w32 = W3r[2];
#pragma unroll
                    for (int px = 0; px < 4; ++px){
                        float acc = a3[o][px];
                        acc = fmaf(v[px + 1], w30, acc);
                        acc = fmaf(v[px + 2], w31, acc);
                        acc = fmaf(v[px + 3], w32, acc);
                        a3[o][px] = acc;
                    }
                }
                if (dy == 2){
#pragma unroll
                    for (int o = 0; o < OCB; ++o){
                        float w10 = w1[(oc0 + o) * 64 + ic];
#pragma unroll
                        for (int px = 0; px < 4; ++px)
                            a1[o][px] = fmaf(v[px + 2], w10, a1[o][px]);
                    }
                }
            }
        }

        // commit prefetched plane to the other buffer; single barrier per ic
        if (ic < 63){
#pragma unroll
            for (int s = 0; s < 6; ++s) sm[nxt][loff[s]] = g[s];
        }
        __syncthreads();
    }

    // write out: 1x4 strip per thread -> 1 float4 per (conv, oc)
    int y = ty0 + ty;
    size_t pix = ((size_t)y << 6) + (k << 2);
    size_t bb = (size_t)b * 320;  // b*5*64
#pragma unroll
    for (int o = 0; o < OCB; ++o){
        int oc = oc0 + o;
        *(float4*)(temp + (((bb + oc) << 12) + pix))       = make_float4(a1[o][0], a1[o][1], a1[o][2], a1[o][3]);
        *(float4*)(temp + (((bb + 64 + oc) << 12) + pix))  = make_float4(a3[o][0], a3[o][1], a3[o][2], a3[o][3]);
        *(float4*)(temp + (((bb + 128 + oc) << 12) + pix)) = make_float4(a5[o][0], a5[o][1], a5[o][2], a5[o][3]);
    }
}

// K5: 3x3 avg (count-normalized) + max pool; xt >= 0 so zero OOB fill is valid for both
__global__ __launch_bounds__(256) void k_pool(const float* __restrict__ xt, float* __restrict__ temp){
    __shared__ float sm[18][18];
    int t = threadIdx.x;
    int tx = t & 15, ty = t >> 4;
    int tile = blockIdx.x, c = blockIdx.y, b = blockIdx.z;
    int ty0 = (tile >> 2) * 16, tx0 = (tile & 3) * 16;
    const float* src = xt + (((size_t)b * 64 + c) << 12);
    for (int i = t; i < 324; i += 256){
        int r = i / 18, cc = i - r * 18;
        int gy = ty0 - 1 + r, gx = tx0 - 1 + cc;
        sm[r][cc] = (gy >= 0 && gy < 64 && gx >= 0 && gx < 64) ? src[(gy << 6) + gx] : 0.f;
    }
    __syncthreads();
    float s = 0.f, m = 0.f;
#pragma unroll
    for (int ky = 0; ky < 3; ++ky)
#pragma unroll
        for (int kx = 0; kx < 3; ++kx){ float v = sm[ty + ky][tx + kx]; s += v; m = fmaxf(m, v); }
    int y = ty0 + ty, x = tx0 + tx;
    int cy = min(y + 1, 63) - max(y - 1, 0) + 1;
    int cx = min(x + 1, 63) - max(x - 1, 0) + 1;
    size_t pix = ((size_t)y << 6) + x;
    size_t bb = (size_t)b * 320;
    temp[((bb + 192 + c) << 12) + pix] = s / (float)(cy * cx);
    temp[((bb + 256 + c) << 12) + pix] = m;
}

// K6: spatial sums of all 384 concat channels (ops 3/4 raw pool sums; op5 from xt)
__global__ __launch_bounds__(256) void k_smean(const float* __restrict__ temp, const float* __restrict__ xt,
                                               float* __restrict__ tsum){
    int opc = blockIdx.x, b = blockIdx.y, t = threadIdx.x;
    const float* src;
    if (opc < 320){
        src = temp + (((size_t)b * 320 + opc) << 12);
    } else {
        src = xt + (((size_t)b * 64 + (opc - 320)) << 12);
    }
    const float4* p = (const float4*)src;
    float s = 0.f;
    for (int i = t; i < 1024; i += 256){ float4 v = p[i]; s += (v.x + v.y) + (v.z + v.w); }
    s = wave_sum(s);
    __shared__ float ss[4];
    int lane = t & 63, w = t >> 6;
    if (!lane) ss[w] = s;
    __syncthreads();
    if (!t) tsum[b * 384 + opc] = ss[0] + ss[1] + ss[2] + ss[3];
}

// K6b: BN stats (mean, rsqrt(var+eps)) over (B,H,W) for the 128 pool channels
__global__ __launch_bounds__(256) void k_bnstats(const float* __restrict__ temp,
                                                 float* __restrict__ bn_m, float* __restrict__ bn_r){
    int q = blockIdx.x, t = threadIdx.x;     // q: 0..127 -> op=3+q/64, c=q%64
    int opc = 192 + q;                        // channel offset within b*320 block
    float s = 0.f, s2 = 0.f;
    for (int b = 0; b < 32; ++b){
        const float4* p = (const float4*)(temp + (((size_t)b * 320 + opc) << 12));
        for (int i = t; i < 1024; i += 256){
            float4 v = p[i];
            s += (v.x + v.y) + (v.z + v.w);
            s2 = fmaf(v.x, v.x, s2); s2 = fmaf(v.y, v.y, s2);
            s2 = fmaf(v.z, v.z, s2); s2 = fmaf(v.w, v.w, s2);
        }
    }
    s = wave_sum(s); s2 = wave_sum(s2);
    __shared__ float ss[4], ss2[4];
    int lane = t & 63, w = t >> 6;
    if (!lane){ ss[w] = s; ss2[w] = s2; }
    __syncthreads();
    if (!t){
        float S = ss[0] + ss[1] + ss[2] + ss[3], S2 = ss2[0] + ss2[1] + ss2[2] + ss2[3];
        const float N = 131072.f;
        float m = S / N;
        float var = S2 / N - m * m;
        bn_m[q] = m;
        bn_r[q] = rsqrtf(var + 1e-5f);
    }
}

// K7: y = sigmoid(relu(tm @ w1.T) @ w2.T); tm adjusts ops3/4 by BN. w1:(48,384), w2:(384,48)
__global__ __launch_bounds__(384) void k_att(const float* __restrict__ tsum, const float* __restrict__ bn_m,
                                             const float* __restrict__ bn_r,
                                             const float* __restrict__ w1, const float* __restrict__ w2,
                                             float* __restrict__ yv){
    int b = blockIdx.x, t = threadIdx.x;
    __shared__ float tm[384], hid[48];
    float v = tsum[b * 384 + t] * (1.f / 4096.f);
    if (t >= 192 && t < 320){ int q = t - 192; v = (v - bn_m[q]) * bn_r[q]; }
    tm[t] = v; __syncthreads();
    if (t < 48){
        float a = 0.f; const float* wr = w1 + t * 384;
        for (int k = 0; k < 384; ++k) a = fmaf(wr[k], tm[k], a);
        hid[t] = fmaxf(a, 0.f);
    }
    __syncthreads();
    float o = 0.f; const float* wr = w2 + t * 48;
    for (int j = 0; j < 48; ++j) o = fmaf(wr[j], hid[j], o);
    yv[b * 384 + t] = 1.f / (1.f + expf(-o));
}

// K8: out = sum_op y_op * op_val (BN folded); scatter to h[:, idx[c]]
__global__ __launch_bounds__(256) void k_combine(const float* __restrict__ temp, const float* __restrict__ xt,
                                                 const float* __restrict__ yv, const float* __restrict__ bn_m,
                                                 const float* __restrict__ bn_r, const int* __restrict__ idxp,
                                                 float* __restrict__ h){
    int c = blockIdx.x, b = blockIdx.y, t = threadIdx.x;
    const float* yb = yv + b * 384;
    float y0 = yb[c], y1 = yb[64 + c], y2 = yb[128 + c];
    float y3 = yb[192 + c], y4 = yb[256 + c], y5 = yb[320 + c];
    float m3 = bn_m[c], r3 = bn_r[c], m4 = bn_m[64 + c], r4 = bn_r[64 + c];
    float a3 = y3 * r3, c3 = -y3 * r3 * m3, a4 = y4 * r4, c4 = -y4 * r4 * m4;
    float bias = c3 + c4;
    size_t base = (((size_t)b * 320 + c) << 12);
    const float4* t0 = (const float4*)(temp + base);
    const float4* t1 = (const float4*)(temp + base + (64ull << 12));
    const float4* t2 = (const float4*)(temp + base + (128ull << 12));
    const float4* t3 = (const float4*)(temp + base + (192ull << 12));
    const float4* t4 = (const float4*)(temp + base + (256ull << 12));
    const float4* t5 = (const float4*)(xt + (((size_t)b * 64 + c) << 12));
    float4* o4 = (float4*)(h + (((size_t)(b * 256 + idxp[c])) << 12));
    for (int i = t; i < 1024; i += 256){
        float4 v0 = t0[i], v1 = t1[i], v2 = t2[i], v3 = t3[i], v4 = t4[i], v5 = t5[i];
        float4 r;
        r.x = y0 * v0.x + y1 * v1.x + y2 * v2.x + a3 * v3.x + a4 * v4.x + y5 * v5.x + bias;
        r.y = y0 * v0.y + y1 * v1.y + y2 * v2.y + a3 * v3.y + a4 * v4.y + y5 * v5.y + bias;
        r.z = y0 * v0.z + y1 * v1.z + y2 * v2.z + a3 * v3.z + a4 * v4.z + y5 * v5.z + bias;
        r.w = y0 * v0.w + y1 * v1.w + y2 * v2.w + a3 * v3.w + a4 * v4.w + y5 * v5.w + bias;
        o4[i] = r;
    }
}

// K9: d_out += x
__global__ __launch_bounds__(256) void k_addx(const float* __restrict__ x, float* __restrict__ out){
    const float4* x4 = (const float4*)x;
    float4* o4 = (float4*)out;
    for (int i = blockIdx.x * 256 + threadIdx.x; i < 8388608; i += 8192 * 256){
        float4 a = x4[i], b = o4[i];
        b.x += a.x; b.y += a.y; b.z += a.z; b.w += a.w;
        o4[i] = b;
    }
}

extern "C" void kernel_launch(void* const* d_in, const int* in_sizes, int n_in,
                              void* d_out, int out_size, void* d_ws, size_t ws_size,
                              hipStream_t stream){
    const float* x = (const float*)d_in[0];
    float* h = (float*)d_out;                 // h buffer lives in d_out
    float* ws = (float*)d_ws;
    float* xt    = ws;                        // 8,388,608 floats
    float* temp  = ws + 8388608;              // 41,943,040 floats (5 ops)
    float* small = ws + 8388608 + 41943040;
    float* meanb = small;                     // 8192
    float* maxb  = small + 8192;              // 8192
    float* nl    = small + 16384;             // 8192
    float* tsum  = small + 24576;             // 12288
    float* bn_m  = small + 36864;             // 128
    float* bn_r  = small + 36992;             // 128
    float* yv    = small + 37120;             // 12288
    int*   idxp  = (int*)(small + 49408);     // 64
    int*   selp  = idxp + 64;                 // 256

    for (int r = 0; r < 2; ++r){
        const float* ca_w1 = (const float*)d_in[2 + r * 7];
        const float* ca_w2 = (const float*)d_in[3 + r * 7];
        const float* w1    = (const float*)d_in[4 + r * 7];
        const float* w3    = (const float*)d_in[5 + r * 7];
        const float* w5    = (const float*)d_in[6 + r * 7];
        const float* a_w1  = (const float*)d_in[7 + r * 7];
        const float* a_w2  = (const float*)d_in[8 + r * 7];
        const float* src = (r == 0) ? x : h;

        hipLaunchKernelGGL(k_meanmax, dim3(8192), dim3(256), 0, stream, src, meanb, maxb);
        hipLaunchKernelGGL(k_nl,      dim3(32),   dim3(256), 0, stream, meanb, maxb, ca_w1, ca_w2, nl);
        hipLaunchKernelGGL(k_topk,    dim3(1),    dim3(256), 0, stream, nl, idxp, selp);
        hipLaunchKernelGGL(k_scale,   dim3(8192), dim3(256), 0, stream, src, h, xt, nl, selp);
        hipLaunchKernelGGL(k_conv,    dim3(4, 16, 32),  dim3(256), 0, stream, xt, w1, w3, w5, temp);
        hipLaunchKernelGGL(k_pool,    dim3(16, 64, 32), dim3(256), 0, stream, xt, temp);
        hipLaunchKernelGGL(k_smean,   dim3(384, 32),    dim3(256), 0, stream, temp, xt, tsum);
        hipLaunchKernelGGL(k_bnstats, dim3(128),  dim3(256), 0, stream, temp, bn_m, bn_r);
        hipLaunchKernelGGL(k_att,     dim3(32),   dim3(384), 0, stream, tsum, bn_m, bn_r, a_w1, a_w2, yv);
        hipLaunchKernelGGL(k_combine, dim3(64, 32), dim3(256), 0, stream, temp, xt, yv, bn_m, bn_r, idxp, h);
    }
    hipLaunchKernelGGL(k_addx, dim3(8192), dim3(256), 0, stream, x, h);
}

// Round 6
// 1486.236 us; speedup vs baseline: 2.4825x; 1.1541x over previous
//
#include <hip/hip_runtime.h>
#include <math.h>

// Shapes: B=32, C=256, H=W=64 (HW=4096), ch=64, ac=384
// h buffer lives in d_out. ws: xt (8.39M f) + temp[5 ops] (41.9M f) + stats.

__device__ __forceinline__ float wave_sum(float v){
#pragma unroll
    for (int o = 32; o; o >>= 1) v += __shfl_down(v, o, 64);
    return v;
}
__device__ __forceinline__ float wave_max(float v){
#pragma unroll
    for (int o = 32; o; o >>= 1) v = fmaxf(v, __shfl_down(v, o, 64));
    return v;
}

// K1: per-(b,c) spatial mean & max of relu(src)
__global__ __launch_bounds__(256) void k_meanmax(const float* __restrict__ src,
                                                 float* __restrict__ meanb,
                                                 float* __restrict__ maxb){
    int bc = blockIdx.x, t = threadIdx.x;
    const float4* p = (const float4*)(src + ((size_t)bc << 12));
    float s = 0.f, m = 0.f;
    for (int i = t; i < 1024; i += 256){
        float4 v = p[i];
        float a = fmaxf(v.x, 0.f), b = fmaxf(v.y, 0.f), c = fmaxf(v.z, 0.f), d = fmaxf(v.w, 0.f);
        s += (a + b) + (c + d);
        m = fmaxf(m, fmaxf(fmaxf(a, b), fmaxf(c, d)));
    }
    s = wave_sum(s); m = wave_max(m);
    __shared__ float ss[4], sm_[4];
    int lane = t & 63, w = t >> 6;
    if (!lane){ ss[w] = s; sm_[w] = m; }
    __syncthreads();
    if (!t){
        meanb[bc] = (ss[0] + ss[1] + ss[2] + ss[3]) * (1.f / 4096.f);
        maxb[bc]  = fmaxf(fmaxf(sm_[0], sm_[1]), fmaxf(sm_[2], sm_[3]));
    }
}

// K2: nl = sigmoid(mlp(mean)+mlp(max)); w1:(128,256), w2:(256,128)
__global__ __launch_bounds__(256) void k_nl(const float* __restrict__ meanb, const float* __restrict__ maxb,
                                            const float* __restrict__ w1, const float* __restrict__ w2,
                                            float* __restrict__ nl){
    int b = blockIdx.x, t = threadIdx.x;
    __shared__ float sm[256], sx[256], hid[128];
    sm[t] = meanb[b * 256 + t]; sx[t] = maxb[b * 256 + t];
    __syncthreads();
    if (t < 128){
        float a = 0.f, c = 0.f;
        const float* wr = w1 + t * 256;
        for (int k = 0; k < 256; ++k){ float w = wr[k]; a = fmaf(w, sm[k], a); c = fmaf(w, sx[k], c); }
        hid[t] = fmaxf(a, 0.f) + fmaxf(c, 0.f);   // relu(h_mean)+relu(h_max), second matmul is linear
    }
    __syncthreads();
    float o = 0.f;
    const float* wr = w2 + t * 128;
    for (int j = 0; j < 128; ++j) o = fmaf(wr[j], hid[j], o);
    nl[b * 256 + t] = 1.f / (1.f + expf(-o));
}

// K2b: slist = nl.sum(0); stable top-64 (value desc, index asc) -> idx[64], selpos[256]
__global__ __launch_bounds__(256) void k_topk(const float* __restrict__ nl,
                                              int* __restrict__ idx, int* __restrict__ selpos){
    int t = threadIdx.x;
    __shared__ float sl[256];
    float s = 0.f;
    for (int b = 0; b < 32; ++b) s += nl[b * 256 + t];
    sl[t] = s; __syncthreads();
    float mys = sl[t];
    int rank = 0;
    for (int c = 0; c < 256; ++c){ float v = sl[c]; rank += (v > mys) || (v == mys && c < t); }
    selpos[t] = (rank < 64) ? rank : -1;
    if (rank < 64) idx[rank] = t;
}

// K3: dst = relu(src)*nl  (all 256 ch); also gather selected channels into xt
__global__ __launch_bounds__(256) void k_scale(const float* __restrict__ src, float* __restrict__ dst,
                                               float* __restrict__ xt, const float* __restrict__ nl,
                                               const int* __restrict__ selpos){
    int bc = blockIdx.x, t = threadIdx.x;
    int b = bc >> 8, c = bc & 255;
    float sc = nl[bc];
    int sp = selpos[c];
    const float4* s4 = (const float4*)(src + ((size_t)bc << 12));
    float4* d4 = (float4*)(dst + ((size_t)bc << 12));
    float4* x4 = (sp >= 0) ? (float4*)(xt + (((size_t)(b * 64 + sp)) << 12)) : (float4*)nullptr;
    for (int i = t; i < 1024; i += 256){
        float4 v = s4[i];
        v.x = fmaxf(v.x, 0.f) * sc; v.y = fmaxf(v.y, 0.f) * sc;
        v.z = fmaxf(v.z, 0.f) * sc; v.w = fmaxf(v.w, 0.f) * sc;
        d4[i] = v;
        if (sp >= 0) x4[i] = v;
    }
}

// K4a/K4b: direct conv on xt (64ch in, 64ch out), SPLIT into 5x5-only and
// 3x3+1x1 kernels so the 5x5 (71% of FMAs) fits the <=64-VGPR class ->
// 8 waves/SIMD (r5 fused kernel: 48 acc forced 76 VGPR -> 4-wave class,
// measured ~3 blocks/CU; 418us VALU vs 239us floor = stalls not hidden).
// Lane map (conflict-light, r5-proven): k=t&15 strip of 4 cols, ty=t>>4,
// tile 16x64, halo 20x68 staged linear; packed offsets (loff<<12|goff)
// save 6 VGPRs. Ping-pong LDS + register prefetch, one barrier per ic.
#define OCB 4
__global__ __launch_bounds__(256, 8) void k_conv5(const float* __restrict__ xt,
                                                  const float* __restrict__ w5,
                                                  float* __restrict__ temp){
    __shared__ __align__(16) float sm[2][1392];
    int t = threadIdx.x;
    int k = t & 15, ty = t >> 4;
    int tile = blockIdx.x;        // 0..3
    int oc0 = blockIdx.y * OCB;   // 0..60
    int b = blockIdx.z;
    int ty0 = tile << 4;

    const float* base = xt + (((size_t)b * 64) << 12);

    int p6[6];
#pragma unroll
    for (int s = 0; s < 6; ++s){
        int i = t + 256 * s;
        int r = i / 68, c = i - r * 68;
        int gy = ty0 - 2 + r, gx = c - 2;
        bool ok = (i < 1360) && gy >= 0 && gy < 64 && gx >= 0 && gx < 64;
        int gof = ok ? ((gy << 6) + gx) : 0;
        int lof = ok ? i : (1360 + (t & 31));
        p6[s] = (lof << 12) | gof;
    }

    for (int i = t; i < 2 * 1392; i += 256) ((float*)sm)[i] = 0.f;
    __syncthreads();
#pragma unroll
    for (int s = 0; s < 6; ++s) sm[0][p6[s] >> 12] = base[p6[s] & 4095];
    __syncthreads();

    float a5[OCB][4];
#pragma unroll
    for (int o = 0; o < OCB; ++o)
#pragma unroll
        for (int px = 0; px < 4; ++px) a5[o][px] = 0.f;

    for (int ic = 0; ic < 64; ++ic){
        int cur = ic & 1, nxt = cur ^ 1;
        float g[6];
        if (ic < 63){
            const float* src = base + ((size_t)(ic + 1) << 12);
#pragma unroll
            for (int s = 0; s < 6; ++s) g[s] = src[p6[s] & 4095];
        }

        const float* smc = sm[cur];
#pragma unroll
        for (int dy = 0; dy < 5; ++dy){
            const float* rowb = smc + (ty + dy) * 68 + (k << 2);
            float4 A = *(const float4*)(rowb);
            float4 Bv = *(const float4*)(rowb + 4);
            float v[8] = {A.x, A.y, A.z, A.w, Bv.x, Bv.y, Bv.z, Bv.w};
#pragma unroll
            for (int o = 0; o < OCB; ++o){
                const float* W5r = w5 + (size_t)((oc0 + o) * 64 + ic) * 25 + dy * 5;
                float w50 = W5r[0], w51 = W5r[1], w52 = W5r[2], w53 = W5r[3], w54 = W5r[4];
#pragma unroll
                for (int px = 0; px < 4; ++px){
                    float acc = a5[o][px];
                    acc = fmaf(v[px + 0], w50, acc);
                    acc = fmaf(v[px + 1], w51, acc);
                    acc = fmaf(v[px + 2], w52, acc);
                    acc = fmaf(v[px + 3], w53, acc);
                    acc = fmaf(v[px + 4], w54, acc);
                    a5[o][px] = acc;
                }
            }
        }

        if (ic < 63){
#pragma unroll
            for (int s = 0; s < 6; ++s) sm[nxt][p6[s] >> 12] = g[s];
        }
        __syncthreads();
    }

    int y = ty0 + ty;
    size_t pix = ((size_t)y << 6) + (k << 2);
    size_t bb = (size_t)b * 320;
#pragma unroll
    for (int o = 0; o < OCB; ++o){
        int oc = oc0 + o;
        *(float4*)(temp + (((bb + 128 + oc) << 12) + pix)) = make_float4(a5[o][0], a5[o][1], a5[o][2], a5[o][3]);
    }
}

__global__ __launch_bounds__(256, 4) void k_conv31(const float* __restrict__ xt,
                                                   const float* __restrict__ w1,
                                                   const float* __restrict__ w3,
                                                   float* __restrict__ temp){
    __shared__ __align__(16) float sm[2][1392];
    int t = threadIdx.x;
    int k = t & 15, ty = t >> 4;
    int tile = blockIdx.x;        // 0..3
    int oc0 = blockIdx.y * OCB;   // 0..60
    int b = blockIdx.z;
    int ty0 = tile << 4;

    const float* base = xt + (((size_t)b * 64) << 12);

    int p6[6];
#pragma unroll
    for (int s = 0; s < 6; ++s){
        int i = t + 256 * s;
        int r = i / 68, c = i - r * 68;
        int gy = ty0 - 2 + r, gx = c - 2;
        bool ok = (i < 1360) && gy >= 0 && gy < 64 && gx >= 0 && gx < 64;
        int gof = ok ? ((gy << 6) + gx) : 0;
        int lof = ok ? i : (1360 + (t & 31));
        p6[s] = (lof << 12) | gof;
    }

    for (int i = t; i < 2 * 1392; i += 256) ((float*)sm)[i] = 0.f;
    __syncthreads();
#pragma unroll
    for (int s = 0; s < 6; ++s) sm[0][p6[s] >> 12] = base[p6[s] & 4095];
    __syncthreads();

    float a1[OCB][4], a3[OCB][4];
#pragma unroll
    for (int o = 0; o < OCB; ++o)
#pragma unroll
        for (int px = 0; px < 4; ++px){ a1[o][px] = 0.f; a3[o][px] = 0.f; }

    for (int ic = 0; ic < 64; ++ic){
        int cur = ic & 1, nxt = cur ^ 1;
        float g[6];
        if (ic < 63){
            const float* src = base + ((size_t)(ic + 1) << 12);
#pragma unroll
            for (int s = 0; s < 6; ++s) g[s] = src[p6[s] & 4095];
        }

        const float* smc = sm[cur];
#pragma unroll
        for (int dy = 1; dy <= 3; ++dy){
            const float* rowb = smc + (ty + dy) * 68 + (k << 2);
            float4 A = *(const float4*)(rowb);
            float4 Bv = *(const float4*)(rowb + 4);
            float v[8] = {A.x, A.y, A.z, A.w, Bv.x, Bv.y, Bv.z, Bv.w};
#pragma unroll
            for (int o = 0; o < OCB; ++o){
                const float* W3r = w3 + (size_t)((oc0 + o) * 64 + ic) * 9 + (dy - 1) * 3;
                float w30 = W3r[0], w31 = W3r[1], w32 = W3r[2];
#pragma unroll
                for (int px = 0; px < 4; ++px){
                    float acc = a3[o][px];
                    acc = fmaf(v[px + 1], w30, acc);
                    acc = fmaf(v[px + 2], w31, acc);
                    acc = fmaf(v[px + 3], w32, acc);
                    a3[o][px] = acc;
                }
            }
            if (dy == 2){
#pragma unroll
                for (int o = 0; o < OCB; ++o){
                    float w10 = w1[(oc0 + o) * 64 + ic];
#pragma unroll
                    for (int px = 0; px < 4; ++px)
                        a1[o][px] = fmaf(v[px + 2], w10, a1[o][px]);
                }
            }
        }

        if (ic < 63){
#pragma unroll
            for (int s = 0; s < 6; ++s) sm[nxt][p6[s] >> 12] = g[s];
        }
        __syncthreads();
    }

    int y = ty0 + ty;
    size_t pix = ((size_t)y << 6) + (k << 2);
    size_t bb = (size_t)b * 320;
#pragma unroll
    for (int o = 0; o < OCB; ++o){
        int oc = oc0 + o;
        *(float4*)(temp + (((bb + oc) << 12) + pix))      = make_float4(a1[o][0], a1[o][1], a1[o][2], a1[o][3]);
        *(float4*)(temp + (((bb + 64 + oc) << 12) + pix)) = make_float4(a3[o][0], a3[o][1], a3[o][2], a3[o][3]);
    }
}

// K5: 3x3 avg (count-normalized) + max pool; xt >= 0 so zero OOB fill is valid for both
__global__ __launch_bounds__(256) void k_pool(const float* __restrict__ xt, float* __restrict__ temp){
    __shared__ float sm[18][18];
    int t = threadIdx.x;
    int tx = t & 15, ty = t >> 4;
    int tile = blockIdx.x, c = blockIdx.y, b = blockIdx.z;
    int ty0 = (tile >> 2) * 16, tx0 = (tile & 3) * 16;
    const float* src = xt + (((size_t)b * 64 + c) << 12);
    for (int i = t; i < 324; i += 256){
        int r = i / 18, cc = i - r * 18;
        int gy = ty0 - 1 + r, gx = tx0 - 1 + cc;
        sm[r][cc] = (gy >= 0 && gy < 64 && gx >= 0 && gx < 64) ? src[(gy << 6) + gx] : 0.f;
    }
    __syncthreads();
    float s = 0.f, m = 0.f;
#pragma unroll
    for (int ky = 0; ky < 3; ++ky)
#pragma unroll
        for (int kx = 0; kx < 3; ++kx){ float v = sm[ty + ky][tx + kx]; s += v; m = fmaxf(m, v); }
    int y = ty0 + ty, x = tx0 + tx;
    int cy = min(y + 1, 63) - max(y - 1, 0) + 1;
    int cx = min(x + 1, 63) - max(x - 1, 0) + 1;
    size_t pix = ((size_t)y << 6) + x;
    size_t bb = (size_t)b * 320;
    temp[((bb + 192 + c) << 12) + pix] = s / (float)(cy * cx);
    temp[((bb + 256 + c) << 12) + pix] = m;
}

// K6: spatial sums of all 384 concat channels (ops 3/4 raw pool sums; op5 from xt)
__global__ __launch_bounds__(256) void k_smean(const float* __restrict__ temp, const float* __restrict__ xt,
                                               float* __restrict__ tsum){
    int opc = blockIdx.x, b = blockIdx.y, t = threadIdx.x;
    const float* src;
    if (opc < 320){
        src = temp + (((size_t)b * 320 + opc) << 12);
    } else {
        src = xt + (((size_t)b * 64 + (opc - 320)) << 12);
    }
    const float4* p = (const float4*)src;
    float s = 0.f;
    for (int i = t; i < 1024; i += 256){ float4 v = p[i]; s += (v.x + v.y) + (v.z + v.w); }
    s = wave_sum(s);
    __shared__ float ss[4];
    int lane = t & 63, w = t >> 6;
    if (!lane) ss[w] = s;
    __syncthreads();
    if (!t) tsum[b * 384 + opc] = ss[0] + ss[1] + ss[2] + ss[3];
}

// K6b: BN stats (mean, rsqrt(var+eps)) over (B,H,W) for the 128 pool channels
__global__ __launch_bounds__(256) void k_bnstats(const float* __restrict__ temp,
                                                 float* __restrict__ bn_m, float* __restrict__ bn_r){
    int q = blockIdx.x, t = threadIdx.x;     // q: 0..127 -> op=3+q/64, c=q%64
    int opc = 192 + q;                        // channel offset within b*320 block
    float s = 0.f, s2 = 0.f;
    for (int b = 0; b < 32; ++b){
        const float4* p = (const float4*)(temp + (((size_t)b * 320 + opc) << 12));
        for (int i = t; i < 1024; i += 256){
            float4 v = p[i];
            s += (v.x + v.y) + (v.z + v.w);
            s2 = fmaf(v.x, v.x, s2); s2 = fmaf(v.y, v.y, s2);
            s2 = fmaf(v.z, v.z, s2); s2 = fmaf(v.w, v.w, s2);
        }
    }
    s = wave_sum(s); s2 = wave_sum(s2);
    __shared__ float ss[4], ss2[4];
    int lane = t & 63, w = t >> 6;
    if (!lane){ ss[w] = s; ss2[w] = s2; }
    __syncthreads();
    if (!t){
        float S = ss[0] + ss[1] + ss[2] + ss[3], S2 = ss2[0] + ss2[1] + ss2[2] + ss2[3];
        const float N = 131072.f;
        float m = S / N;
        float var = S2 / N - m * m;
        bn_m[q] = m;
        bn_r[q] = rsqrtf(var + 1e-5f);
    }
}

// K7: y = sigmoid(relu(tm @ w1.T) @ w2.T); tm adjusts ops3/4 by BN. w1:(48,384), w2:(384,48)
__global__ __launch_bounds__(384) void k_att(const float* __restrict__ tsum, const float* __restrict__ bn_m,
                                             const float* __restrict__ bn_r,
                                             const float* __restrict__ w1, const float* __restrict__ w2,
                                             float* __restrict__ yv){
    int b = blockIdx.x, t = threadIdx.x;
    __shared__ float tm[384], hid[48];
    float v = tsum[b * 384 + t] * (1.f / 4096.f);
    if (t >= 192 && t < 320){ int q = t - 192; v = (v - bn_m[q]) * bn_r[q]; }
    tm[t] = v; __syncthreads();
    if (t < 48){
        float a = 0.f; const float* wr = w1 + t * 384;
        for (int k = 0; k < 384; ++k) a = fmaf(wr[k], tm[k], a);
        hid[t] = fmaxf(a, 0.f);
    }
    __syncthreads();
    float o = 0.f; const float* wr = w2 + t * 48;
    for (int j = 0; j < 48; ++j) o = fmaf(wr[j], hid[j], o);
    yv[b * 384 + t] = 1.f / (1.f + expf(-o));
}

// K8: out = sum_op y_op * op_val (BN folded); scatter to h[:, idx[c]]
__global__ __launch_bounds__(256) void k_combine(const float* __restrict__ temp, const float* __restrict__ xt,
                                                 const float* __restrict__ yv, const float* __restrict__ bn_m,
                                                 const float* __restrict__ bn_r, const int* __restrict__ idxp,
                                                 float* __restrict__ h){
    int c = blockIdx.x, b = blockIdx.y, t = threadIdx.x;
    const float* yb = yv + b * 384;
    float y0 = yb[c], y1 = yb[64 + c], y2 = yb[128 + c];
    float y3 = yb[192 + c], y4 = yb[256 + c], y5 = yb[320 + c];
    float m3 = bn_m[c], r3 = bn_r[c], m4 = bn_m[64 + c], r4 = bn_r[64 + c];
    float a3 = y3 * r3, c3 = -y3 * r3 * m3, a4 = y4 * r4, c4 = -y4 * r4 * m4;
    float bias = c3 + c4;
    size_t base = (((size_t)b * 320 + c) << 12);
    const float4* t0 = (const float4*)(temp + base);
    const float4* t1 = (const float4*)(temp + base + (64ull << 12));
    const float4* t2 = (const float4*)(temp + base + (128ull << 12));
    const float4* t3 = (const float4*)(temp + base + (192ull << 12));
    const float4* t4 = (const float4*)(temp + base + (256ull << 12));
    const float4* t5 = (const float4*)(xt + (((size_t)b * 64 + c) << 12));
    float4* o4 = (float4*)(h + (((size_t)(b * 256 + idxp[c])) << 12));
    for (int i = t; i < 1024; i += 256){
        float4 v0 = t0[i], v1 = t1[i], v2 = t2[i], v3 = t3[i], v4 = t4[i], v5 = t5[i];
        float4 r;
        r.x = y0 * v0.x + y1 * v1.x + y2 * v2.x + a3 * v3.x + a4 * v4.x + y5 * v5.x + bias;
        r.y = y0 * v0.y + y1 * v1.y + y2 * v2.y + a3 * v3.y + a4 * v4.y + y5 * v5.y + bias;
        r.z = y0 * v0.z + y1 * v1.z + y2 * v2.z + a3 * v3.z + a4 * v4.z + y5 * v5.z + bias;
        r.w = y0 * v0.w + y1 * v1.w + y2 * v2.w + a3 * v3.w + a4 * v4.w + y5 * v5.w + bias;
        o4[i] = r;
    }
}

// K9: d_out += x
__global__ __launch_bounds__(256) void k_addx(const float* __restrict__ x, float* __restrict__ out){
    const float4* x4 = (const float4*)x;
    float4* o4 = (float4*)out;
    for (int i = blockIdx.x * 256 + threadIdx.x; i < 8388608; i += 8192 * 256){
        float4 a = x4[i], b = o4[i];
        b.x += a.x; b.y += a.y; b.z += a.z; b.w += a.w;
        o4[i] = b;
    }
}

extern "C" void kernel_launch(void* const* d_in, const int* in_sizes, int n_in,
                              void* d_out, int out_size, void* d_ws, size_t ws_size,
                              hipStream_t stream){
    const float* x = (const float*)d_in[0];
    float* h = (float*)d_out;                 // h buffer lives in d_out
    float* ws = (float*)d_ws;
    float* xt    = ws;                        // 8,388,608 floats
    float* temp  = ws + 8388608;              // 41,943,040 floats (5 ops)
    float* small = ws + 8388608 + 41943040;
    float* meanb = small;                     // 8192
    float* maxb  = small + 8192;              // 8192
    float* nl    = small + 16384;             // 8192
    float* tsum  = small + 24576;             // 12288
    float* bn_m  = small + 36864;             // 128
    float* bn_r  = small + 36992;             // 128
    float* yv    = small + 37120;             // 12288
    int*   idxp  = (int*)(small + 49408);     // 64
    int*   selp  = idxp + 64;                 // 256

    for (int r = 0; r < 2; ++r){
        const float* ca_w1 = (const float*)d_in[2 + r * 7];
        const float* ca_w2 = (const float*)d_in[3 + r * 7];
        const float* w1    = (const float*)d_in[4 + r * 7];
        const float* w3    = (const float*)d_in[5 + r * 7];
        const float* w5    = (const float*)d_in[6 + r * 7];
        const float* a_w1  = (const float*)d_in[7 + r * 7];
        const float* a_w2  = (const float*)d_in[8 + r * 7];
        const float* src = (r == 0) ? x : h;

        hipLaunchKernelGGL(k_meanmax, dim3(8192), dim3(256), 0, stream, src, meanb, maxb);
        hipLaunchKernelGGL(k_nl,      dim3(32),   dim3(256), 0, stream, meanb, maxb, ca_w1, ca_w2, nl);
        hipLaunchKernelGGL(k_topk,    dim3(1),    dim3(256), 0, stream, nl, idxp, selp);
        hipLaunchKernelGGL(k_scale,   dim3(8192), dim3(256), 0, stream, src, h, xt, nl, selp);
        hipLaunchKernelGGL(k_conv5,   dim3(4, 16, 32),  dim3(256), 0, stream, xt, w5, temp);
        hipLaunchKernelGGL(k_conv31,  dim3(4, 16, 32),  dim3(256), 0, stream, xt, w1, w3, temp);
        hipLaunchKernelGGL(k_pool,    dim3(16, 64, 32), dim3(256), 0, stream, xt, temp);
        hipLaunchKernelGGL(k_smean,   dim3(384, 32),    dim3(256), 0, stream, temp, xt, tsum);
        hipLaunchKernelGGL(k_bnstats, dim3(128),  dim3(256), 0, stream, temp, bn_m, bn_r);
        hipLaunchKernelGGL(k_att,     dim3(32),   dim3(384), 0, stream, tsum, bn_m, bn_r, a_w1, a_w2, yv);
        hipLaunchKernelGGL(k_combine, dim3(64, 32), dim3(256), 0, stream, temp, xt, yv, bn_m, bn_r, idxp, h);
    }
    hipLaunchKernelGGL(k_addx, dim3(8192), dim3(256), 0, stream, x, h);
}

// Round 7
// 1417.470 us; speedup vs baseline: 2.6030x; 1.0485x over previous
//
#include <hip/hip_runtime.h>
#include <math.h>

// Shapes: B=32, C=256, H=W=64 (HW=4096), ch=64, ac=384
// h buffer lives in d_out. ws: guard(32f) + xt (8.39M f) + temp (41.9M f) + stats.

__device__ __forceinline__ float wave_sum(float v){
#pragma unroll
    for (int o = 32; o; o >>= 1) v += __shfl_down(v, o, 64);
    return v;
}
__device__ __forceinline__ float wave_max(float v){
#pragma unroll
    for (int o = 32; o; o >>= 1) v = fmaxf(v, __shfl_down(v, o, 64));
    return v;
}

// K1: per-(b,c) spatial mean & max of relu(src)
__global__ __launch_bounds__(256) void k_meanmax(const float* __restrict__ src,
                                                 float* __restrict__ meanb,
                                                 float* __restrict__ maxb){
    int bc = blockIdx.x, t = threadIdx.x;
    const float4* p = (const float4*)(src + ((size_t)bc << 12));
    float s = 0.f, m = 0.f;
    for (int i = t; i < 1024; i += 256){
        float4 v = p[i];
        float a = fmaxf(v.x, 0.f), b = fmaxf(v.y, 0.f), c = fmaxf(v.z, 0.f), d = fmaxf(v.w, 0.f);
        s += (a + b) + (c + d);
        m = fmaxf(m, fmaxf(fmaxf(a, b), fmaxf(c, d)));
    }
    s = wave_sum(s); m = wave_max(m);
    __shared__ float ss[4], sm_[4];
    int lane = t & 63, w = t >> 6;
    if (!lane){ ss[w] = s; sm_[w] = m; }
    __syncthreads();
    if (!t){
        meanb[bc] = (ss[0] + ss[1] + ss[2] + ss[3]) * (1.f / 4096.f);
        maxb[bc]  = fmaxf(fmaxf(sm_[0], sm_[1]), fmaxf(sm_[2], sm_[3]));
    }
}

// K2: nl = sigmoid(mlp(mean)+mlp(max)); w1:(128,256), w2:(256,128)
__global__ __launch_bounds__(256) void k_nl(const float* __restrict__ meanb, const float* __restrict__ maxb,
                                            const float* __restrict__ w1, const float* __restrict__ w2,
                                            float* __restrict__ nl){
    int b = blockIdx.x, t = threadIdx.x;
    __shared__ float sm[256], sx[256], hid[128];
    sm[t] = meanb[b * 256 + t]; sx[t] = maxb[b * 256 + t];
    __syncthreads();
    if (t < 128){
        float a = 0.f, c = 0.f;
        const float* wr = w1 + t * 256;
        for (int k = 0; k < 256; ++k){ float w = wr[k]; a = fmaf(w, sm[k], a); c = fmaf(w, sx[k], c); }
        hid[t] = fmaxf(a, 0.f) + fmaxf(c, 0.f);   // relu(h_mean)+relu(h_max), second matmul is linear
    }
    __syncthreads();
    float o = 0.f;
    const float* wr = w2 + t * 128;
    for (int j = 0; j < 128; ++j) o = fmaf(wr[j], hid[j], o);
    nl[b * 256 + t] = 1.f / (1.f + expf(-o));
}

// K2b: slist = nl.sum(0); stable top-64; also zeros the conv zero-row buffer
__global__ __launch_bounds__(256) void k_topk(const float* __restrict__ nl,
                                              int* __restrict__ idx, int* __restrict__ selpos,
                                              float* __restrict__ zpad){
    int t = threadIdx.x;
    if (t < 128) zpad[t] = 0.f;
    __shared__ float sl[256];
    float s = 0.f;
    for (int b = 0; b < 32; ++b) s += nl[b * 256 + t];
    sl[t] = s; __syncthreads();
    float mys = sl[t];
    int rank = 0;
    for (int c = 0; c < 256; ++c){ float v = sl[c]; rank += (v > mys) || (v == mys && c < t); }
    selpos[t] = (rank < 64) ? rank : -1;
    if (rank < 64) idx[rank] = t;
}

// K3: dst = relu(src)*nl  (all 256 ch); also gather selected channels into xt
__global__ __launch_bounds__(256) void k_scale(const float* __restrict__ src, float* __restrict__ dst,
                                               float* __restrict__ xt, const float* __restrict__ nl,
                                               const int* __restrict__ selpos){
    int bc = blockIdx.x, t = threadIdx.x;
    int b = bc >> 8, c = bc & 255;
    float sc = nl[bc];
    int sp = selpos[c];
    const float4* s4 = (const float4*)(src + ((size_t)bc << 12));
    float4* d4 = (float4*)(dst + ((size_t)bc << 12));
    float4* x4 = (sp >= 0) ? (float4*)(xt + (((size_t)(b * 64 + sp)) << 12)) : (float4*)nullptr;
    for (int i = t; i < 1024; i += 256){
        float4 v = s4[i];
        v.x = fmaxf(v.x, 0.f) * sc; v.y = fmaxf(v.y, 0.f) * sc;
        v.z = fmaxf(v.z, 0.f) * sc; v.w = fmaxf(v.w, 0.f) * sc;
        d4[i] = v;
        if (sp >= 0) x4[i] = v;
    }
}

// K4a/K4b: LDS-FREE direct conv (r6 evidence: LDS conflicts ~18cyc/read across
// 3 layouts = 154us/CU pipe time; L1 can serve the 5.8KB/block/ic working set
// with ~10x reuse instead). Thread owns a 1x4 strip; per (ic,dy): 3 aligned
// float4 global loads (cols 4k-4..4k+7), window v[0..7]=cols 4k-2..4k+5.
// Row OOB -> pointer redirected to zpad (zeroed 128f); x-edge -> cndmask zero
// v[0,1] (k==0) / v[6,7] (k==15). col-4 underrun covered by 32f guard at ws
// start. No barriers, no staging regs: live ~80 (32 acc) at (256,4).
#define OCB5 8
__global__ __launch_bounds__(256, 4) void k_conv5(const float* __restrict__ xt,
                                                  const float* __restrict__ w5,
                                                  const float* __restrict__ zpad,
                                                  float* __restrict__ temp){
    int t = threadIdx.x;
    int k = t & 15, ty = t >> 4;
    int tile = blockIdx.x;        // 0..3
    int oc0 = blockIdx.y * OCB5;  // 0..56
    int b = blockIdx.z;
    int ty0 = tile << 4;
    int ybase = ty0 + ty - 2;
    bool k0 = (k == 0), k15 = (k == 15);
    const float* zrow = zpad + 8 + (k << 2);

    float a5[OCB5][4];
#pragma unroll
    for (int o = 0; o < OCB5; ++o)
#pragma unroll
        for (int px = 0; px < 4; ++px) a5[o][px] = 0.f;

    for (int ic = 0; ic < 64; ++ic){
        const float* bi = xt + (((size_t)(b * 64 + ic)) << 12) + (k << 2);
#pragma unroll
        for (int dy = 0; dy < 5; ++dy){
            int gy = ybase + dy;
            const float* rp = ((unsigned)gy < 64u) ? (bi + (gy << 6)) : zrow;
            float4 A  = *(const float4*)(rp - 4);
            float4 Bv = *(const float4*)(rp);
            float4 Cv = *(const float4*)(rp + 4);
            float v[8];
            v[0] = k0 ? 0.f : A.z;  v[1] = k0 ? 0.f : A.w;
            v[2] = Bv.x; v[3] = Bv.y; v[4] = Bv.z; v[5] = Bv.w;
            v[6] = k15 ? 0.f : Cv.x; v[7] = k15 ? 0.f : Cv.y;
#pragma unroll
            for (int o = 0; o < OCB5; ++o){
                const float* W5r = w5 + (size_t)((oc0 + o) * 64 + ic) * 25 + dy * 5;
                float w50 = W5r[0], w51 = W5r[1], w52 = W5r[2], w53 = W5r[3], w54 = W5r[4];
#pragma unroll
                for (int px = 0; px < 4; ++px){
                    float acc = a5[o][px];
                    acc = fmaf(v[px + 0], w50, acc);
                    acc = fmaf(v[px + 1], w51, acc);
                    acc = fmaf(v[px + 2], w52, acc);
                    acc = fmaf(v[px + 3], w53, acc);
                    acc = fmaf(v[px + 4], w54, acc);
                    a5[o][px] = acc;
                }
            }
        }
    }

    int y = ty0 + ty;
    size_t pix = ((size_t)y << 6) + (k << 2);
    size_t bb = (size_t)b * 320;
#pragma unroll
    for (int o = 0; o < OCB5; ++o){
        int oc = oc0 + o;
        *(float4*)(temp + (((bb + 128 + oc) << 12) + pix)) = make_float4(a5[o][0], a5[o][1], a5[o][2], a5[o][3]);
    }
}

#define OCB3 4
__global__ __launch_bounds__(256, 4) void k_conv31(const float* __restrict__ xt,
                                                   const float* __restrict__ w1,
                                                   const float* __restrict__ w3,
                                                   const float* __restrict__ zpad,
                                                   float* __restrict__ temp){
    int t = threadIdx.x;
    int k = t & 15, ty = t >> 4;
    int tile = blockIdx.x;        // 0..3
    int oc0 = blockIdx.y * OCB3;  // 0..60
    int b = blockIdx.z;
    int ty0 = tile << 4;
    int ybase = ty0 + ty - 1;
    bool k0 = (k == 0), k15 = (k == 15);
    const float* zrow = zpad + 8 + (k << 2);

    float a1[OCB3][4], a3[OCB3][4];
#pragma unroll
    for (int o = 0; o < OCB3; ++o)
#pragma unroll
        for (int px = 0; px < 4; ++px){ a1[o][px] = 0.f; a3[o][px] = 0.f; }

    for (int ic = 0; ic < 64; ++ic){
        const float* bi = xt + (((size_t)(b * 64 + ic)) << 12) + (k << 2);
#pragma unroll
        for (int dy = 0; dy < 3; ++dy){
            int gy = ybase + dy;
            const float* rp = ((unsigned)gy < 64u) ? (bi + (gy << 6)) : zrow;
            float4 Bv = *(const float4*)(rp);
            float  al = *(rp - 1);
            float  cr = *(rp + 4);
            float v[6];
            v[0] = k0 ? 0.f : al;
            v[1] = Bv.x; v[2] = Bv.y; v[3] = Bv.z; v[4] = Bv.w;
            v[5] = k15 ? 0.f : cr;
#pragma unroll
            for (int o = 0; o < OCB3; ++o){
                const float* W3r = w3 + (size_t)((oc0 + o) * 64 + ic) * 9 + dy * 3;
                float w30 = W3r[0], w31 = W3r[1], w32 = W3r[2];
#pragma unroll
                for (int px = 0; px < 4; ++px){
                    float acc = a3[o][px];
                    acc = fmaf(v[px + 0], w30, acc);
                    acc = fmaf(v[px + 1], w31, acc);
                    acc = fmaf(v[px + 2], w32, acc);
                    a3[o][px] = acc;
                }
            }
            if (dy == 1){
#pragma unroll
                for (int o = 0; o < OCB3; ++o){
                    float w10 = w1[(oc0 + o) * 64 + ic];
#pragma unroll
                    for (int px = 0; px < 4; ++px)
                        a1[o][px] = fmaf(v[px + 1], w10, a1[o][px]);
                }
            }
        }
    }

    int y = ty0 + ty;
    size_t pix = ((size_t)y << 6) + (k << 2);
    size_t bb = (size_t)b * 320;
#pragma unroll
    for (int o = 0; o < OCB3; ++o){
        int oc = oc0 + o;
        *(float4*)(temp + (((bb + oc) << 12) + pix))      = make_float4(a1[o][0], a1[o][1], a1[o][2], a1[o][3]);
        *(float4*)(temp + (((bb + 64 + oc) << 12) + pix)) = make_float4(a3[o][0], a3[o][1], a3[o][2], a3[o][3]);
    }
}

// K5: 3x3 avg (count-normalized) + max pool; xt >= 0 so zero OOB fill is valid for both
__global__ __launch_bounds__(256) void k_pool(const float* __restrict__ xt, float* __restrict__ temp){
    __shared__ float sm[18][18];
    int t = threadIdx.x;
    int tx = t & 15, ty = t >> 4;
    int tile = blockIdx.x, c = blockIdx.y, b = blockIdx.z;
    int ty0 = (tile >> 2) * 16, tx0 = (tile & 3) * 16;
    const float* src = xt + (((size_t)b * 64 + c) << 12);
    for (int i = t; i < 324; i += 256){
        int r = i / 18, cc = i - r * 18;
        int gy = ty0 - 1 + r, gx = tx0 - 1 + cc;
        sm[r][cc] = (gy >= 0 && gy < 64 && gx >= 0 && gx < 64) ? src[(gy << 6) + gx] : 0.f;
    }
    __syncthreads();
    float s = 0.f, m = 0.f;
#pragma unroll
    for (int ky = 0; ky < 3; ++ky)
#pragma unroll
        for (int kx = 0; kx < 3; ++kx){ float v = sm[ty + ky][tx + kx]; s += v; m = fmaxf(m, v); }
    int y = ty0 + ty, x = tx0 + tx;
    int cy = min(y + 1, 63) - max(y - 1, 0) + 1;
    int cx = min(x + 1, 63) - max(x - 1, 0) + 1;
    size_t pix = ((size_t)y << 6) + x;
    size_t bb = (size_t)b * 320;
    temp[((bb + 192 + c) << 12) + pix] = s / (float)(cy * cx);
    temp[((bb + 256 + c) << 12) + pix] = m;
}

// K6: spatial sums of all 384 concat channels (ops 3/4 raw pool sums; op5 from xt)
__global__ __launch_bounds__(256) void k_smean(const float* __restrict__ temp, const float* __restrict__ xt,
                                               float* __restrict__ tsum){
    int opc = blockIdx.x, b = blockIdx.y, t = threadIdx.x;
    const float* src;
    if (opc < 320){
        src = temp + (((size_t)b * 320 + opc) << 12);
    } else {
        src = xt + (((size_t)b * 64 + (opc - 320)) << 12);
    }
    const float4* p = (const float4*)src;
    float s = 0.f;
    for (int i = t; i < 1024; i += 256){ float4 v = p[i]; s += (v.x + v.y) + (v.z + v.w); }
    s = wave_sum(s);
    __shared__ float ss[4];
    int lane = t & 63, w = t >> 6;
    if (!lane) ss[w] = s;
    __syncthreads();
    if (!t) tsum[b * 384 + opc] = ss[0] + ss[1] + ss[2] + ss[3];
}

// K6b: BN stats (mean, rsqrt(var+eps)) over (B,H,W) for the 128 pool channels
__global__ __launch_bounds__(256) void k_bnstats(const float* __restrict__ temp,
                                                 float* __restrict__ bn_m, float* __restrict__ bn_r){
    int q = blockIdx.x, t = threadIdx.x;     // q: 0..127 -> op=3+q/64, c=q%64
    int opc = 192 + q;                        // channel offset within b*320 block
    float s = 0.f, s2 = 0.f;
    for (int b = 0; b < 32; ++b){
        const float4* p = (const float4*)(temp + (((size_t)b * 320 + opc) << 12));
        for (int i = t; i < 1024; i += 256){
            float4 v = p[i];
            s += (v.x + v.y) + (v.z + v.w);
            s2 = fmaf(v.x, v.x, s2); s2 = fmaf(v.y, v.y, s2);
            s2 = fmaf(v.z, v.z, s2); s2 = fmaf(v.w, v.w, s2);
        }
    }
    s = wave_sum(s); s2 = wave_sum(s2);
    __shared__ float ss[4], ss2[4];
    int lane = t & 63, w = t >> 6;
    if (!lane){ ss[w] = s; ss2[w] = s2; }
    __syncthreads();
    if (!t){
        float S = ss[0] + ss[1] + ss[2] + ss[3], S2 = ss2[0] + ss2[1] + ss2[2] + ss2[3];
        const float N = 131072.f;
        float m = S / N;
        float var = S2 / N - m * m;
        bn_m[q] = m;
        bn_r[q] = rsqrtf(var + 1e-5f);
    }
}

// K7: y = sigmoid(relu(tm @ w1.T) @ w2.T); tm adjusts ops3/4 by BN. w1:(48,384), w2:(384,48)
__global__ __launch_bounds__(384) void k_att(const float* __restrict__ tsum, const float* __restrict__ bn_m,
                                             const float* __restrict__ bn_r,
                                             const float* __restrict__ w1, const float* __restrict__ w2,
                                             float* __restrict__ yv){
    int b = blockIdx.x, t = threadIdx.x;
    __shared__ float tm[384], hid[48];
    float v = tsum[b * 384 + t] * (1.f / 4096.f);
    if (t >= 192 && t < 320){ int q = t - 192; v = (v - bn_m[q]) * bn_r[q]; }
    tm[t] = v; __syncthreads();
    if (t < 48){
        float a = 0.f; const float* wr = w1 + t * 384;
        for (int k = 0; k < 384; ++k) a = fmaf(wr[k], tm[k], a);
        hid[t] = fmaxf(a, 0.f);
    }
    __syncthreads();
    float o = 0.f; const float* wr = w2 + t * 48;
    for (int j = 0; j < 48; ++j) o = fmaf(wr[j], hid[j], o);
    yv[b * 384 + t] = 1.f / (1.f + expf(-o));
}

// K8: out = sum_op y_op * op_val (BN folded); scatter to h[:, idx[c]]
__global__ __launch_bounds__(256) void k_combine(const float* __restrict__ temp, const float* __restrict__ xt,
                                                 const float* __restrict__ yv, const float* __restrict__ bn_m,
                                                 const float* __restrict__ bn_r, const int* __restrict__ idxp,
                                                 float* __restrict__ h){
    int c = blockIdx.x, b = blockIdx.y, t = threadIdx.x;
    const float* yb = yv + b * 384;
    float y0 = yb[c], y1 = yb[64 + c], y2 = yb[128 + c];
    float y3 = yb[192 + c], y4 = yb[256 + c], y5 = yb[320 + c];
    float m3 = bn_m[c], r3 = bn_r[c], m4 = bn_m[64 + c], r4 = bn_r[64 + c];
    float a3 = y3 * r3, c3 = -y3 * r3 * m3, a4 = y4 * r4, c4 = -y4 * r4 * m4;
    float bias = c3 + c4;
    size_t base = (((size_t)b * 320 + c) << 12);
    const float4* t0 = (const float4*)(temp + base);
    const float4* t1 = (const float4*)(temp + base + (64ull << 12));
    const float4* t2 = (const float4*)(temp + base + (128ull << 12));
    const float4* t3 = (const float4*)(temp + base + (192ull << 12));
    const float4* t4 = (const float4*)(temp + base + (256ull << 12));
    const float4* t5 = (const float4*)(xt + (((size_t)b * 64 + c) << 12));
    float4* o4 = (float4*)(h + (((size_t)(b * 256 + idxp[c])) << 12));
    for (int i = t; i < 1024; i += 256){
        float4 v0 = t0[i], v1 = t1[i], v2 = t2[i], v3 = t3[i], v4 = t4[i], v5 = t5[i];
        float4 r;
        r.x = y0 * v0.x + y1 * v1.x + y2 * v2.x + a3 * v3.x + a4 * v4.x + y5 * v5.x + bias;
        r.y = y0 * v0.y + y1 * v1.y + y2 * v2.y + a3 * v3.y + a4 * v4.y + y5 * v5.y + bias;
        r.z = y0 * v0.z + y1 * v1.z + y2 * v2.z + a3 * v3.z + a4 * v4.z + y5 * v5.z + bias;
        r.w = y0 * v0.w + y1 * v1.w + y2 * v2.w + a3 * v3.w + a4 * v4.w + y5 * v5.w + bias;
        o4[i] = r;
    }
}

// K9: d_out += x
__global__ __launch_bounds__(256) void k_addx(const float* __restrict__ x, float* __restrict__ out){
    const float4* x4 = (const float4*)x;
    float4* o4 = (float4*)out;
    for (int i = blockIdx.x * 256 + threadIdx.x; i < 8388608; i += 8192 * 256){
        float4 a = x4[i], b = o4[i];
        b.x += a.x; b.y += a.y; b.z += a.z; b.w += a.w;
        o4[i] = b;
    }
}

extern "C" void kernel_launch(void* const* d_in, const int* in_sizes, int n_in,
                              void* d_out, int out_size, void* d_ws, size_t ws_size,
                              hipStream_t stream){
    const float* x = (const float*)d_in[0];
    float* h = (float*)d_out;                 // h buffer lives in d_out
    float* ws = (float*)d_ws;
    float* xt    = ws + 32;                   // 32-float guard before xt (conv col-4 underrun)
    float* temp  = xt + 8388608;              // 41,943,040 floats (5 ops)
    float* small = temp + 41943040;
    float* meanb = small;                     // 8192
    float* maxb  = small + 8192;              // 8192
    float* nl    = small + 16384;             // 8192
    float* tsum  = small + 24576;             // 12288
    float* bn_m  = small + 36864;             // 128
    float* bn_r  = small + 36992;             // 128
    float* yv    = small + 37120;             // 12288
    int*   idxp  = (int*)(small + 49408);     // 64
    int*   selp  = idxp + 64;                 // 256
    float* zpad  = small + 49792;             // 128 floats, zeroed by k_topk

    for (int r = 0; r < 2; ++r){
        const float* ca_w1 = (const float*)d_in[2 + r * 7];
        const float* ca_w2 = (const float*)d_in[3 + r * 7];
        const float* w1    = (const float*)d_in[4 + r * 7];
        const float* w3    = (const float*)d_in[5 + r * 7];
        const float* w5    = (const float*)d_in[6 + r * 7];
        const float* a_w1  = (const float*)d_in[7 + r * 7];
        const float* a_w2  = (const float*)d_in[8 + r * 7];
        const float* src = (r == 0) ? x : h;

        hipLaunchKernelGGL(k_meanmax, dim3(8192), dim3(256), 0, stream, src, meanb, maxb);
        hipLaunchKernelGGL(k_nl,      dim3(32),   dim3(256), 0, stream, meanb, maxb, ca_w1, ca_w2, nl);
        hipLaunchKernelGGL(k_topk,    dim3(1),    dim3(256), 0, stream, nl, idxp, selp, zpad);
        hipLaunchKernelGGL(k_scale,   dim3(8192), dim3(256), 0, stream, src, h, xt, nl, selp);
        hipLaunchKernelGGL(k_conv5,   dim3(4, 8, 32),   dim3(256), 0, stream, xt, w5, zpad, temp);
        hipLaunchKernelGGL(k_conv31,  dim3(4, 16, 32),  dim3(256), 0, stream, xt, w1, w3, zpad, temp);
        hipLaunchKernelGGL(k_pool,    dim3(16, 64, 32), dim3(256), 0, stream, xt, temp);
        hipLaunchKernelGGL(k_smean,   dim3(384, 32),    dim3(256), 0, stream, temp, xt, tsum);
        hipLaunchKernelGGL(k_bnstats, dim3(128),  dim3(256), 0, stream, temp, bn_m, bn_r);
        hipLaunchKernelGGL(k_att,     dim3(32),   dim3(384), 0, stream, tsum, bn_m, bn_r, a_w1, a_w2, yv);
        hipLaunchKernelGGL(k_combine, dim3(64, 32), dim3(256), 0, stream, temp, xt, yv, bn_m, bn_r, idxp, h);
    }
    hipLaunchKernelGGL(k_addx, dim3(8192), dim3(256), 0, stream, x, h);
}